// Round 5
// baseline (416.269 us; speedup 1.0000x reference)
//
#include <hip/hip_runtime.h>
#include <stdint.h>

// Problem constants: x [B=2, S=4096, K=4096] -> M = 8192; weight [N=4096, K=4096]
#define M_DIM 8192
#define N_DIM 4096
#define K_DIM 4096

using int4v = __attribute__((ext_vector_type(4))) int;

// ---------------------------------------------------------------------------
// Pack kernel: int32 (widened int8 in [-127,127]) -> int8 bytes.
// One int4 (16 B) read per thread -> 4 B write, fully coalesced.
// ---------------------------------------------------------------------------
__global__ __launch_bounds__(256) void pack_kernel(const int4* __restrict__ sx,
                                                   const int4* __restrict__ sw,
                                                   unsigned int* __restrict__ dst,
                                                   int nx, int ntot) {
    int idx = blockIdx.x * blockDim.x + threadIdx.x;
    if (idx >= ntot) return;
    int4 v = (idx < nx) ? sx[idx] : sw[idx - nx];
    dst[idx] = (v.x & 0xff) | ((v.y & 0xff) << 8) | ((v.z & 0xff) << 16) |
               ((v.w & 0xff) << 24);
}

// ---------------------------------------------------------------------------
// Async global -> LDS copy, 16 B per lane (global_load_lds_dwordx4).
// LDS destination is wave-uniform base + lane*16 (no per-lane scatter).
// ---------------------------------------------------------------------------
__device__ __forceinline__ void async_copy16(const char* g, char* l) {
    __builtin_amdgcn_global_load_lds(
        (const __attribute__((address_space(1))) char*)g,
        (__attribute__((address_space(3))) char*)l, 16, 0, 0);
}

// ---------------------------------------------------------------------------
// i8 GEMM: 128x128 block tile, 256 threads = 4 waves in 2x2, each wave owns a
// 64x64 tile as 4x4 grid of 16x16 MFMA tiles (mfma_i32_16x16x64_i8, BK=64).
// Single-buffer, 2-barrier K-loop (round-2 structure; dbuf measured neutral).
//
// LDS BANK-CONFLICT SWIZZLE: tile row-major [128][64] in 16-B chunks
// (row, gs); LDS chunk (row, gs) stores GLOBAL column-group gs ^ ((row>>1)&3).
// Frag-read lane (row=fr, gw) -> bank-group (4*fr + gw^((fr>>1)&3)) % 8 hits
// all 8 four-bank groups across fr=0..7 -> 2-way aliasing only (free, m136).
// Staging still reads 64 contiguous B per row (perm within row) -> coalesced,
// and LDS dst stays lane-contiguous (global_load_lds constraint).
//
// C[m,n] = sum_k x[m,k] * w[n,k]  (both operands K-major).
// A/B frag: m=lane&15, k-group=lane>>4.  C/D: col=lane&15, row=(lane>>4)*4+reg.
// ---------------------------------------------------------------------------
__global__ __launch_bounds__(256, 2) void gemm_i8_kernel(
    const char* __restrict__ Aq,   // [M, K] int8
    const char* __restrict__ Bq,   // [N, K] int8
    const int* __restrict__ bias,  // [N] int32 (widened int8)
    const float* __restrict__ a_ptr,
    const float* __restrict__ b_ptr,
    int32_t* __restrict__ out)     // [M, N] int32 holding int8 values
{
    __shared__ char As[128 * 64];
    __shared__ char Bs[128 * 64];

    const int tid  = threadIdx.x;
    const int lane = tid & 63;
    const int wave = tid >> 6;
    const int wr   = wave >> 1;   // wave row (0..1) -> 64-row slab
    const int wc   = wave & 1;    // wave col (0..1) -> 64-col slab
    const int m0   = blockIdx.y * 128;
    const int n0   = blockIdx.x * 128;

    const float alpha = *a_ptr;
    const float beta  = *b_ptr;

    int4v acc[4][4] = {};  // 64 accumulator regs

    // Staging: thread t fills LDS chunk t (row = t>>2, gs = t&3). The global
    // source column-group is swizzled: g = gs ^ ((row>>1)&3).
    const int srow = tid >> 2;                        // 0..63
    const int sg   = (tid & 3) ^ ((srow >> 1) & 3);   // swizzled col-group
    const int scol = sg * 16;

    const char* aG0 = Aq + (size_t)(m0 + srow) * K_DIM + scol;
    const char* aG1 = aG0 + (size_t)64 * K_DIM;       // rows+64: key unchanged
    const char* bG0 = Bq + (size_t)(n0 + srow) * K_DIM + scol;
    const char* bG1 = bG0 + (size_t)64 * K_DIM;
    char* aL0 = &As[tid * 16];
    char* aL1 = &As[tid * 16 + 4096];
    char* bL0 = &Bs[tid * 16];
    char* bL1 = &Bs[tid * 16 + 4096];

    // Fragment read coordinates: lane holds A[m = lane&15][k-group = lane>>4].
    // Swizzle key depends only on (fr>>1)&3 (wr*64 and i*16 are 0 mod period).
    const int fr  = lane & 15;
    const int gw  = lane >> 4;
    const int fko = (gw ^ ((fr >> 1) & 3)) * 16;      // swizzled byte offset

    for (int k0 = 0; k0 < K_DIM; k0 += 64) {
        async_copy16(aG0 + k0, aL0);
        async_copy16(aG1 + k0, aL1);
        async_copy16(bG0 + k0, bL0);
        async_copy16(bG1 + k0, bL1);
        __syncthreads();  // drains vmcnt(0) -> LDS tiles valid

        int4v af[4], bf[4];
#pragma unroll
        for (int i = 0; i < 4; ++i)
            af[i] = *(const int4v*)&As[(wr * 64 + i * 16 + fr) * 64 + fko];
#pragma unroll
        for (int j = 0; j < 4; ++j)
            bf[j] = *(const int4v*)&Bs[(wc * 64 + j * 16 + fr) * 64 + fko];

#pragma unroll
        for (int i = 0; i < 4; ++i)
#pragma unroll
            for (int j = 0; j < 4; ++j)
                acc[i][j] = __builtin_amdgcn_mfma_i32_16x16x64_i8(
                    af[i], bf[j], acc[i][j], 0, 0, 0);

        __syncthreads();  // all reads done before next-iter staging overwrites
    }

    // Epilogue: C/D layout col = lane&15, row = (lane>>4)*4 + reg.
    const int orow = (lane >> 4) * 4;
    const int ocol = lane & 15;
#pragma unroll
    for (int j = 0; j < 4; ++j) {
        const int gn = n0 + wc * 64 + j * 16 + ocol;
        const float bb = beta * (float)bias[gn];
#pragma unroll
        for (int i = 0; i < 4; ++i) {
            const int gm = m0 + wr * 64 + i * 16 + orow;
#pragma unroll
            for (int r = 0; r < 4; ++r) {
                float v = alpha * (float)acc[i][j][r] + bb;
                v = rintf(v);                       // round half-to-even (numpy)
                v = fminf(fmaxf(v, -128.0f), 127.0f);
                out[(size_t)(gm + r) * N_DIM + gn] = (int32_t)v;
            }
        }
    }
}

// ---------------------------------------------------------------------------
extern "C" void kernel_launch(void* const* d_in, const int* in_sizes, int n_in,
                              void* d_out, int out_size, void* d_ws, size_t ws_size,
                              hipStream_t stream) {
    const int*   x    = (const int*)d_in[0];    // [M, K] widened int8
    const int*   w    = (const int*)d_in[1];    // [N, K] widened int8
    const int*   bias = (const int*)d_in[2];    // [N]
    const float* a    = (const float*)d_in[3];  // alpha scalar
    const float* b    = (const float*)d_in[4];  // beta scalar
    int32_t*     out  = (int32_t*)d_out;        // [M, N]

    char* xq = (char*)d_ws;                     // 32 MiB packed x
    const int nx   = (M_DIM * K_DIM) / 4;       // int4-groups in x
    const int nw   = (N_DIM * K_DIM) / 4;
    const int ntot = nx + nw;
    pack_kernel<<<(ntot + 255) / 256, 256, 0, stream>>>(
        (const int4*)x, (const int4*)w, (unsigned int*)xq, nx, ntot);

    char* wq = xq + (size_t)M_DIM * K_DIM;      // 16 MiB packed weight

    dim3 grid(N_DIM / 128, M_DIM / 128);        // 32 x 64 = 2048 blocks
    gemm_i8_kernel<<<grid, 256, 0, stream>>>(xq, wq, bias, a, b, out);
}

// Round 6
// 406.648 us; speedup vs baseline: 1.0237x; 1.0237x over previous
//
#include <hip/hip_runtime.h>
#include <stdint.h>

// Problem constants: x [B=2, S=4096, K=4096] -> M = 8192; weight [N=4096, K=4096]
#define M_DIM 8192
#define N_DIM 4096
#define K_DIM 4096

using int4v = __attribute__((ext_vector_type(4))) int;

// ---------------------------------------------------------------------------
// Pack kernel: int32 (widened int8 in [-127,127]) -> int8 bytes.
// One int4 (16 B) read per thread -> 4 B write, fully coalesced.
// ---------------------------------------------------------------------------
__global__ __launch_bounds__(256) void pack_kernel(const int4* __restrict__ sx,
                                                   const int4* __restrict__ sw,
                                                   unsigned int* __restrict__ dst,
                                                   int nx, int ntot) {
    int idx = blockIdx.x * blockDim.x + threadIdx.x;
    if (idx >= ntot) return;
    int4 v = (idx < nx) ? sx[idx] : sw[idx - nx];
    dst[idx] = (v.x & 0xff) | ((v.y & 0xff) << 8) | ((v.z & 0xff) << 16) |
               ((v.w & 0xff) << 24);
}

// ---------------------------------------------------------------------------
// Async global -> LDS copy, 16 B per lane (global_load_lds_dwordx4).
// LDS destination is wave-uniform base + lane*16 (no per-lane scatter).
// ---------------------------------------------------------------------------
__device__ __forceinline__ void async_copy16(const char* g, char* l) {
    __builtin_amdgcn_global_load_lds(
        (const __attribute__((address_space(1))) char*)g,
        (__attribute__((address_space(3))) char*)l, 16, 0, 0);
}

// ---------------------------------------------------------------------------
// i8 GEMM: 128(M) x 256(N) block tile, 256 threads = 4 waves in 2x2; each
// wave owns a 64x128 tile as 4x8 grid of 16x16 MFMA tiles
// (mfma_i32_16x16x64_i8, BK=64). Rationale (r5 counters): LDS pipe (62%) +
// MFMA (39%) saturate the CU; frag reads scale with tile perimeter, MFMA
// with area -> 64x128 wave tile cuts LDS-read cyc/MAC by 1.33x and halves
// barriers/MAC. LDS: A 128x64 (8KB) + B 256x64 (16KB) = 24 KiB.
//
// LDS bank swizzle (r5, measured conflicts -> 0): 16-B chunk (row, gs) in
// LDS stores global col-group gs ^ ((row>>1)&3); read side XOR-corrects.
//
// C[m,n] = sum_k x[m,k] * w[n,k]  (both operands K-major).
// A/B frag: m=lane&15, k-group=lane>>4.  C/D: col=lane&15, row=(lane>>4)*4+reg.
// ---------------------------------------------------------------------------
__global__ __launch_bounds__(256, 2) void gemm_i8_kernel(
    const char* __restrict__ Aq,   // [M, K] int8
    const char* __restrict__ Bq,   // [N, K] int8
    const int* __restrict__ bias,  // [N] int32 (widened int8)
    const float* __restrict__ a_ptr,
    const float* __restrict__ b_ptr,
    int32_t* __restrict__ out)     // [M, N] int32 holding int8 values
{
    __shared__ char As[128 * 64];   // 8 KiB
    __shared__ char Bs[256 * 64];   // 16 KiB

    const int tid  = threadIdx.x;
    const int lane = tid & 63;
    const int wave = tid >> 6;
    const int wr   = wave >> 1;   // wave row (0..1) -> 64 M-rows
    const int wc   = wave & 1;    // wave col (0..1) -> 128 N-cols
    const int m0   = blockIdx.y * 128;
    const int n0   = blockIdx.x * 256;

    const float alpha = *a_ptr;
    const float beta  = *b_ptr;

    int4v acc[4][8] = {};  // 128 accumulator regs (AGPR)

    // Staging: thread t owns chunk rows r = t>>2 (+64k), swizzled col-group.
    const int srow = tid >> 2;                        // 0..63
    const int scol = ((tid & 3) ^ ((srow >> 1) & 3)) * 16;

    // A: 2 chunks (rows srow, srow+64). B: 4 chunks (rows srow + 64c).
    const char* aG0 = Aq + (size_t)(m0 + srow) * K_DIM + scol;
    const char* aG1 = aG0 + (size_t)64 * K_DIM;
    const char* bG0 = Bq + (size_t)(n0 + srow) * K_DIM + scol;
    const char* bG1 = bG0 + (size_t)64 * K_DIM;
    const char* bG2 = bG0 + (size_t)128 * K_DIM;
    const char* bG3 = bG0 + (size_t)192 * K_DIM;
    char* aL0 = &As[tid * 16];
    char* aL1 = &As[tid * 16 + 4096];
    char* bL0 = &Bs[tid * 16];
    char* bL1 = &Bs[tid * 16 + 4096];
    char* bL2 = &Bs[tid * 16 + 8192];
    char* bL3 = &Bs[tid * 16 + 12288];

    // Fragment read coords: lane holds A[m = lane&15][k-group = lane>>4],
    // with the swizzle XOR folded into the byte offset (key = (fr>>1)&3;
    // wr*64, wc*128, i*16, j*16 are all 0 mod the 8-row swizzle period).
    const int fr  = lane & 15;
    const int gw  = lane >> 4;
    const int fko = (gw ^ ((fr >> 1) & 3)) * 16;

    for (int k0 = 0; k0 < K_DIM; k0 += 64) {
        async_copy16(aG0 + k0, aL0);
        async_copy16(aG1 + k0, aL1);
        async_copy16(bG0 + k0, bL0);
        async_copy16(bG1 + k0, bL1);
        async_copy16(bG2 + k0, bL2);
        async_copy16(bG3 + k0, bL3);
        __syncthreads();  // drains vmcnt(0) -> LDS tiles valid

        int4v af[4], bf[8];
#pragma unroll
        for (int i = 0; i < 4; ++i)
            af[i] = *(const int4v*)&As[(wr * 64 + i * 16 + fr) * 64 + fko];
#pragma unroll
        for (int j = 0; j < 8; ++j)
            bf[j] = *(const int4v*)&Bs[(wc * 128 + j * 16 + fr) * 64 + fko];

#pragma unroll
        for (int i = 0; i < 4; ++i)
#pragma unroll
            for (int j = 0; j < 8; ++j)
                acc[i][j] = __builtin_amdgcn_mfma_i32_16x16x64_i8(
                    af[i], bf[j], acc[i][j], 0, 0, 0);

        __syncthreads();  // all reads done before next-iter staging overwrites
    }

    // Epilogue: C/D layout col = lane&15, row = (lane>>4)*4 + reg.
    const int orow = (lane >> 4) * 4;
    const int ocol = lane & 15;
#pragma unroll
    for (int j = 0; j < 8; ++j) {
        const int gn = n0 + wc * 128 + j * 16 + ocol;
        const float bb = beta * (float)bias[gn];
#pragma unroll
        for (int i = 0; i < 4; ++i) {
            const int gm = m0 + wr * 64 + i * 16 + orow;
#pragma unroll
            for (int r = 0; r < 4; ++r) {
                float v = alpha * (float)acc[i][j][r] + bb;
                v = rintf(v);                       // round half-to-even (numpy)
                v = fminf(fmaxf(v, -128.0f), 127.0f);
                out[(size_t)(gm + r) * N_DIM + gn] = (int32_t)v;
            }
        }
    }
}

// ---------------------------------------------------------------------------
extern "C" void kernel_launch(void* const* d_in, const int* in_sizes, int n_in,
                              void* d_out, int out_size, void* d_ws, size_t ws_size,
                              hipStream_t stream) {
    const int*   x    = (const int*)d_in[0];    // [M, K] widened int8
    const int*   w    = (const int*)d_in[1];    // [N, K] widened int8
    const int*   bias = (const int*)d_in[2];    // [N]
    const float* a    = (const float*)d_in[3];  // alpha scalar
    const float* b    = (const float*)d_in[4];  // beta scalar
    int32_t*     out  = (int32_t*)d_out;        // [M, N]

    char* xq = (char*)d_ws;                     // 32 MiB packed x
    const int nx   = (M_DIM * K_DIM) / 4;       // int4-groups in x
    const int nw   = (N_DIM * K_DIM) / 4;
    const int ntot = nx + nw;
    pack_kernel<<<(ntot + 255) / 256, 256, 0, stream>>>(
        (const int4*)x, (const int4*)w, (unsigned int*)xq, nx, ntot);

    char* wq = xq + (size_t)M_DIM * K_DIM;      // 16 MiB packed weight

    dim3 grid(N_DIM / 256, M_DIM / 128);        // 16 x 64 = 1024 blocks
    gemm_i8_kernel<<<grid, 256, 0, stream>>>(xq, wq, bias, a, b, out);
}